// Round 4
// baseline (2172.082 us; speedup 1.0000x reference)
//
#include <hip/hip_runtime.h>
#include <math.h>

#define NN   50000
#define TT   2
#define CC   768
#define GG   16
#define EE   800000
#define HH   192
#define OUTD 3
#define MR   (NN*TT)   // 100000 rows
#define FD   (TT*HH)   // 384 features per node
#define EPS_GN 1e-5f
#define AGG_CH 128
#define NREP 8

typedef __attribute__((ext_vector_type(8))) short bf16x8;
typedef __attribute__((ext_vector_type(4))) float f32x4;

__device__ __forceinline__ float gelu_exact(float x){
    return 0.5f * x * (1.0f + erff(x * 0.70710678118654752440f));
}

__device__ __forceinline__ short f2b(float f){   // RNE float->bf16
    unsigned u = __float_as_uint(f);
    unsigned r = (u + 0x7FFFu + ((u>>16)&1u)) >> 16;
    return (short)r;
}
__device__ __forceinline__ float b2f(unsigned short u){
    return __uint_as_float(((unsigned)u)<<16);
}

// ---------- degree ----------
__global__ __launch_bounds__(256) void k_deg(const int* __restrict__ dst, float* __restrict__ deg){
    int e = blockIdx.x*256 + threadIdx.x;
    if(e < EE) atomicAdd(&deg[dst[e]], 1.0f);
}

// ---------- weight convert: W[K][192] fp32 -> Wt[192][K] bf16 ----------
__global__ __launch_bounds__(256) void k_wconv(const float* __restrict__ W0, const float* __restrict__ W1,
                                               const float* __restrict__ Wh1,
                                               short* __restrict__ Wt0, short* __restrict__ Wt1,
                                               short* __restrict__ Wth1){
    int i = blockIdx.x*256 + threadIdx.x;
    if(i < CC*HH){
        int k = i / HH, n = i % HH;
        Wt0[(size_t)n*CC + k] = f2b(W0[i]);
    }
    if(i < HH*HH){
        int k = i / HH, n = i % HH;
        Wt1 [(size_t)n*HH + k] = f2b(W1[i]);
        Wth1[(size_t)n*HH + k] = f2b(Wh1[i]);
    }
}

// ---------- CSR build (scan1 also emits dinv; scan2 also emits cnt) ----------
__global__ __launch_bounds__(256) void k_scan1(const float* __restrict__ deg, int* __restrict__ partial,
                                               float* __restrict__ dinv){
    __shared__ int s[256];
    int t = threadIdx.x;
    int i = blockIdx.x*256 + t;
    float dv = (i < NN) ? deg[i] : 0.f;
    if(i < NN) dinv[i] = rsqrtf(dv + 1.0f);
    int v = (int)dv;
    s[t] = v; __syncthreads();
    for(int off=128; off>0; off>>=1){ if(t < off) s[t] += s[t+off]; __syncthreads(); }
    if(t == 0) partial[blockIdx.x] = s[0];
}

__global__ __launch_bounds__(256) void k_scan2(int* __restrict__ partial, const int* __restrict__ batch,
                                               float* __restrict__ cnt){
    __shared__ int s[256];
    int t = threadIdx.x;
    if(t < GG){   // fused group-count (batch is sorted)
        int g = t;
        int lo0=0, hi=NN;
        while(lo0<hi){ int mid=(lo0+hi)>>1; if(batch[mid] < g) lo0=mid+1; else hi=mid; }
        int lo1=lo0; hi=NN;
        while(lo1<hi){ int mid=(lo1+hi)>>1; if(batch[mid] < g+1) lo1=mid+1; else hi=mid; }
        cnt[g] = (float)(lo1 - lo0);
    }
    int v = partial[t];
    s[t] = v; __syncthreads();
    for(int off=1; off<256; off<<=1){
        int x = (t >= off) ? s[t-off] : 0;
        __syncthreads();
        s[t] += x;
        __syncthreads();
    }
    partial[t] = s[t] - v;
}

__global__ __launch_bounds__(256) void k_scan3(const float* __restrict__ deg, const int* __restrict__ partial,
                                               int* __restrict__ csr_off){
    __shared__ int s[256];
    int t = threadIdx.x;
    int i = blockIdx.x*256 + t;
    int v = (i < NN) ? (int)deg[i] : 0;
    s[t] = v; __syncthreads();
    for(int off=1; off<256; off<<=1){
        int x = (t >= off) ? s[t-off] : 0;
        __syncthreads();
        s[t] += x;
        __syncthreads();
    }
    if(i < NN) csr_off[i] = partial[blockIdx.x] + s[t] - v;
}

__global__ __launch_bounds__(256) void k_fill(const int* __restrict__ src, const int* __restrict__ dst,
                                              const int* __restrict__ csr_off, int* __restrict__ fillcnt,
                                              int* __restrict__ csr_src){
    int e = blockIdx.x*256 + threadIdx.x;
    if(e < EE){
        int d = dst[e];
        int pos = csr_off[d] + atomicAdd(&fillcnt[d], 1);
        csr_src[pos] = src[e];
    }
}

// ---------- GraphNorm+GELU on 8 register-resident values ----------
__device__ __forceinline__ void gn8r(float4 u0, float4 u1,
                                     const float* __restrict__ sm, const float* __restrict__ sq,
                                     int sb, int hb_,
                                     const float* __restrict__ wg, const float* __restrict__ bg,
                                     const float* __restrict__ ag, float ic, float v[8]){
    float4 m0 = *(const float4*)(sm+sb),   m1 = *(const float4*)(sm+sb+4);
    float4 q0 = *(const float4*)(sq+sb),   q1 = *(const float4*)(sq+sb+4);
    float4 w0 = *(const float4*)(wg+hb_),  w1 = *(const float4*)(wg+hb_+4);
    float4 b0 = *(const float4*)(bg+hb_),  b1 = *(const float4*)(bg+hb_+4);
    float4 a0 = *(const float4*)(ag+hb_),  a1 = *(const float4*)(ag+hb_+4);
    float uu[8]={u0.x,u0.y,u0.z,u0.w,u1.x,u1.y,u1.z,u1.w};
    float mm[8]={m0.x,m0.y,m0.z,m0.w,m1.x,m1.y,m1.z,m1.w};
    float qq[8]={q0.x,q0.y,q0.z,q0.w,q1.x,q1.y,q1.z,q1.w};
    float ww[8]={w0.x,w0.y,w0.z,w0.w,w1.x,w1.y,w1.z,w1.w};
    float bb[8]={b0.x,b0.y,b0.z,b0.w,b1.x,b1.y,b1.z,b1.w};
    float aa[8]={a0.x,a0.y,a0.z,a0.w,a1.x,a1.y,a1.z,a1.w};
    #pragma unroll
    for(int j=0;j<8;j++){
        float mean = mm[j]*ic, ex2 = qq[j]*ic, al = aa[j];
        float var = ex2 - (2.0f*al - al*al)*mean*mean;
        float t = ww[j]*(uu[j] - al*mean)*rsqrtf(var + EPS_GN) + bb[j];
        v[j] = gelu_exact(t);
    }
}

// ---------- bf16 MFMA GEMM (2-phase register prefetch; LDS-staged A and B) ----------
// MODE 1: write bf16 C.  MODE 2: head-fused -> out[M][3] = gelu(C+bias) @ W2 + b2
// NORM 0: A raw fp32.  NORM 1: A = gelu(gn(A1; stats1)).  NORM 2: A = gelu(gn(A1;s1)) + gelu(gn(A0;s0))
template<int MODE, int NORM, bool BIAS>
__global__ __launch_bounds__(256) void k_gemm_mfma(
        const float* __restrict__ A1, const float* __restrict__ A0,
        const short* __restrict__ Bt,
        const float* __restrict__ bias, void* __restrict__ Cv,
        const float* __restrict__ W2, const float* __restrict__ b2,
        const int* __restrict__ batch, const float* __restrict__ cnt,
        const float* __restrict__ sm1, const float* __restrict__ sq1,
        const float* __restrict__ wg1, const float* __restrict__ bg1, const float* __restrict__ ag1,
        const float* __restrict__ sm0, const float* __restrict__ sq0,
        const float* __restrict__ wg0, const float* __restrict__ bg0, const float* __restrict__ ag0,
        int Mrows, int Kdim){
    __shared__ short As[64][40];
    __shared__ short Bs[192][40];
    int tid = threadIdx.x;
    int bm = blockIdx.x*64;
    int wv = tid>>6, lane = tid&63;
    int lm = lane&15, lq = lane>>4;

    f32x4 acc[12];
    #pragma unroll
    for(int i=0;i<12;i++) acc[i] = (f32x4){0.f,0.f,0.f,0.f};

    int ar = tid>>2, akg = (tid&3)<<3;
    int row = bm + ar;
    bool aok = row < Mrows;
    const float* Ap1 = A1 + (size_t)row*Kdim + akg;
    const float* Ap0 = (NORM==2) ? (A0 + (size_t)row*Kdim + akg) : nullptr;
    int g = 0, tT = 0; float ic = 0.f;
    if(NORM >= 1 && aok){
        int nn = row>>1; tT = row&1;
        g = batch[nn];
        ic = 1.0f / cnt[g];
    }

    // register staging state (prefetched one K-step ahead)
    float4 ra0 = make_float4(0,0,0,0), ra1 = ra0, rb0 = ra0, rb1 = ra0;
    bf16x8 bv[3];
    if(aok){
        ra0 = *(const float4*)(Ap1); ra1 = *(const float4*)(Ap1 + 4);
        if(NORM==2){ rb0 = *(const float4*)(Ap0); rb1 = *(const float4*)(Ap0 + 4); }
    }
    #pragma unroll
    for(int i=0;i<3;i++){
        int idx = tid + i*256;
        int n = idx>>2, kg = (idx&3)<<3;
        bv[i] = *(const bf16x8*)(Bt + (size_t)n*Kdim + kg);
    }

    for(int k0 = 0; k0 < Kdim; k0 += 32){
        // convert the prefetched A regs -> bf16 fragment (VALU only)
        bf16x8 ap = {};
        if(aok){
            if(NORM == 0){
                ap[0]=f2b(ra0.x); ap[1]=f2b(ra0.y); ap[2]=f2b(ra0.z); ap[3]=f2b(ra0.w);
                ap[4]=f2b(ra1.x); ap[5]=f2b(ra1.y); ap[6]=f2b(ra1.z); ap[7]=f2b(ra1.w);
            } else {
                int hb_ = akg + k0;            // per-channel index (Kdim==HH here)
                int sb  = g*FD + tT*HH + hb_;
                float v[8];
                gn8r(ra0, ra1, sm1, sq1, sb, hb_, wg1, bg1, ag1, ic, v);
                if(NORM == 2){
                    float v0[8];
                    gn8r(rb0, rb1, sm0, sq0, sb, hb_, wg0, bg0, ag0, ic, v0);
                    #pragma unroll
                    for(int j=0;j<8;j++) v[j] += v0[j];
                }
                #pragma unroll
                for(int j=0;j<8;j++) ap[j] = f2b(v[j]);
            }
        }
        bf16x8 bw0 = bv[0], bw1 = bv[1], bw2 = bv[2];
        __syncthreads();
        *(bf16x8*)&As[ar][akg] = ap;
        {
            int idx0 = tid, idx1 = tid+256, idx2 = tid+512;
            *(bf16x8*)&Bs[idx0>>2][(idx0&3)<<3] = bw0;
            *(bf16x8*)&Bs[idx1>>2][(idx1&3)<<3] = bw1;
            *(bf16x8*)&Bs[idx2>>2][(idx2&3)<<3] = bw2;
        }
        __syncthreads();
        // issue next K-step's global loads before the MFMA cluster
        int k1 = k0 + 32;
        if(k1 < Kdim){
            if(aok){
                ra0 = *(const float4*)(Ap1 + k1); ra1 = *(const float4*)(Ap1 + k1 + 4);
                if(NORM==2){ rb0 = *(const float4*)(Ap0 + k1); rb1 = *(const float4*)(Ap0 + k1 + 4); }
            }
            #pragma unroll
            for(int i=0;i<3;i++){
                int idx = tid + i*256;
                int n = idx>>2, kg = (idx&3)<<3;
                bv[i] = *(const bf16x8*)(Bt + (size_t)n*Kdim + k1 + kg);
            }
        }
        bf16x8 af = *(const bf16x8*)&As[wv*16 + lm][lq*8];
        #pragma unroll
        for(int ct=0; ct<12; ct++){
            bf16x8 bfr = *(const bf16x8*)&Bs[ct*16 + lm][lq*8];
            acc[ct] = __builtin_amdgcn_mfma_f32_16x16x32_bf16(af, bfr, acc[ct], 0, 0, 0);
        }
    }

    if(MODE == 1){
        short* C = (short*)Cv;
        #pragma unroll
        for(int ct=0; ct<12; ct++){
            int col = ct*16 + lm;
            float bs = BIAS ? bias[col] : 0.f;
            #pragma unroll
            for(int r=0; r<4; r++){
                int orow = bm + wv*16 + lq*4 + r;
                if(orow < Mrows) C[(size_t)orow*HH + col] = f2b(acc[ct][r] + bs);
            }
        }
    } else {  // MODE 2: fused head
        float hs[4][3] = {};
        #pragma unroll
        for(int ct=0; ct<12; ct++){
            int col = ct*16 + lm;
            float bs = bias[col];
            float w20 = W2[col*3+0], w21 = W2[col*3+1], w22 = W2[col*3+2];
            #pragma unroll
            for(int r=0; r<4; r++){
                float gl = gelu_exact(acc[ct][r] + bs);
                hs[r][0] += gl*w20; hs[r][1] += gl*w21; hs[r][2] += gl*w22;
            }
        }
        #pragma unroll
        for(int off=1; off<16; off<<=1){
            #pragma unroll
            for(int r=0;r<4;r++){
                hs[r][0] += __shfl_xor(hs[r][0], off);
                hs[r][1] += __shfl_xor(hs[r][1], off);
                hs[r][2] += __shfl_xor(hs[r][2], off);
            }
        }
        if(lm == 0){
            float* O = (float*)Cv;
            #pragma unroll
            for(int r=0;r<4;r++){
                int orow = bm + wv*16 + lq*4 + r;
                if(orow < Mrows){
                    O[(size_t)orow*3+0] = hs[r][0] + b2[0];
                    O[(size_t)orow*3+1] = hs[r][1] + b2[1];
                    O[(size_t)orow*3+2] = hs[r][2] + b2[2];
                }
            }
        }
    }
}

// ---------- GCN aggregation + fused GraphNorm stats (8 contention replicas) ----------
__global__ __launch_bounds__(192) void k_agg(const ushort* __restrict__ hw, const int* __restrict__ csr_src,
                                             const int* __restrict__ csr_off, const float* __restrict__ deg,
                                             const float* __restrict__ dinv, const float* __restrict__ bias,
                                             const int* __restrict__ batch,
                                             float* __restrict__ out,
                                             float* __restrict__ ssum8, float* __restrict__ ssq8){
    __shared__ int   sidx[AGG_CH];
    __shared__ float swt [AGG_CH];
    int n = blockIdx.x;
    int t = threadIdx.x;                 // 0..191, features 2t, 2t+1
    float di = dinv[n];
    const ushort2* H2 = (const ushort2*)hw;
    ushort2 sv = H2[(size_t)n*192 + t];
    float self = di*di;
    float ax = b2f(sv.x)*self, ay = b2f(sv.y)*self;
    int beg = csr_off[n];
    int end = beg + (int)deg[n];
    for(int base = beg; base < end; base += AGG_CH){
        int m = min(AGG_CH, end - base);
        __syncthreads();
        for(int j = t; j < m; j += 192){
            int s = csr_src[base + j];
            sidx[j] = s;
            swt[j] = dinv[s]*di;
        }
        __syncthreads();
        int j = 0;
        for(; j+8 <= m; j += 8){
            int   si[8]; float wt[8]; ushort2 vv[8];
            #pragma unroll
            for(int q=0;q<8;q++){ si[q]=sidx[j+q]; wt[q]=swt[j+q]; }
            #pragma unroll
            for(int q=0;q<8;q++) vv[q] = H2[(size_t)si[q]*192 + t];
            #pragma unroll
            for(int q=0;q<8;q++){ ax += wt[q]*b2f(vv[q].x); ay += wt[q]*b2f(vv[q].y); }
        }
        for(; j < m; j++){
            int s = sidx[j]; float ww = swt[j];
            ushort2 v = H2[(size_t)s*192 + t];
            ax += ww*b2f(v.x); ay += ww*b2f(v.y);
        }
    }
    int f = 2*t;
    int hh = (f < HH) ? f : f - HH;
    float vx = ax + bias[hh];
    float vy = ay + bias[hh+1];
    out[(size_t)n*FD + f]   = vx;
    out[(size_t)n*FD + f+1] = vy;
    // fused GraphNorm stats: per-group sum / sumsq, 8 replicas to bound same-address depth
    int g = batch[n];
    size_t sbase = ((size_t)(n & (NREP-1))*GG + g)*FD + f;
    atomicAdd(&ssum8[sbase],   vx);
    atomicAdd(&ssum8[sbase+1], vy);
    atomicAdd(&ssq8 [sbase],   vx*vx);
    atomicAdd(&ssq8 [sbase+1], vy*vy);
}

// ---------- fold the 8 stat replicas ----------
__global__ __launch_bounds__(256) void k_gn_reduce(const float* __restrict__ sm8, const float* __restrict__ sq8,
                                                   float* __restrict__ fm, float* __restrict__ fq){
    int i = blockIdx.x*256 + threadIdx.x;
    if(i < GG*FD){
        float a = 0.f, b = 0.f;
        #pragma unroll
        for(int r=0;r<NREP;r++){
            a += sm8[(size_t)r*GG*FD + i];
            b += sq8[(size_t)r*GG*FD + i];
        }
        fm[i] = a; fq[i] = b;
    }
}

extern "C" void kernel_launch(void* const* d_in, const int* in_sizes, int n_in,
                              void* d_out, int out_size, void* d_ws, size_t ws_size,
                              hipStream_t stream){
    const float* x     = (const float*)d_in[0];
    const int*   batch = (const int*)d_in[1];
    const int*   ei    = (const int*)d_in[2];
    const int*   src   = ei;
    const int*   dst   = ei + EE;
    const float* W0    = (const float*)d_in[3];
    const float* b0    = (const float*)d_in[4];
    const float* gn0_w = (const float*)d_in[5];
    const float* gn0_b = (const float*)d_in[6];
    const float* gn0_a = (const float*)d_in[7];
    const float* W1    = (const float*)d_in[8];
    const float* b1    = (const float*)d_in[9];
    const float* gn1_w = (const float*)d_in[10];
    const float* gn1_b = (const float*)d_in[11];
    const float* gn1_a = (const float*)d_in[12];
    const float* Wh1   = (const float*)d_in[13];
    const float* bh1   = (const float*)d_in[14];
    const float* Wh2   = (const float*)d_in[15];
    const float* bh2   = (const float*)d_in[16];
    float* out = (float*)d_out;

    char* w = (char*)d_ws;
    auto alloc = [&](size_t bytes)->void*{
        void* p = (void*)w;
        w += (bytes + 255) & ~(size_t)255;
        return p;
    };
    char* zbase = w;
    float* deg     = (float*)alloc((size_t)NN*4);
    int*   fillcnt = (int*)  alloc((size_t)NN*4);
    int*   partial = (int*)  alloc(256*4);
    float* s0m8    = (float*)alloc((size_t)NREP*GG*FD*4);
    float* s0q8    = (float*)alloc((size_t)NREP*GG*FD*4);
    float* s1m8    = (float*)alloc((size_t)NREP*GG*FD*4);
    float* s1q8    = (float*)alloc((size_t)NREP*GG*FD*4);
    size_t zbytes = (size_t)(w - zbase);
    float* f0m     = (float*)alloc((size_t)GG*FD*4);
    float* f0q     = (float*)alloc((size_t)GG*FD*4);
    float* f1m     = (float*)alloc((size_t)GG*FD*4);
    float* f1q     = (float*)alloc((size_t)GG*FD*4);
    float* cnt     = (float*)alloc((size_t)GG*4);
    float* dinv    = (float*)alloc((size_t)NN*4);
    int*   csr_off = (int*)  alloc((size_t)NN*4);
    int*   csr_src = (int*)  alloc((size_t)EE*4);
    short* Wt0     = (short*)alloc((size_t)HH*CC*2);
    short* Wt1     = (short*)alloc((size_t)HH*HH*2);
    short* Wth1    = (short*)alloc((size_t)HH*HH*2);
    short* hb0     = (short*)alloc((size_t)MR*HH*2);   // bf16 GEMM0 output (agg0 input)
    short* hb1     = (short*)alloc((size_t)MR*HH*2);   // bf16 GEMM1 output (agg1 input)
    float* agg0    = (float*)alloc((size_t)MR*HH*4);   // fp32 pre-norm layer0 (kept for residual)
    float* agg1    = (float*)alloc((size_t)MR*HH*4);   // fp32 pre-norm layer1

    hipMemsetAsync(zbase, 0, zbytes, stream);

    k_deg  <<<(EE+255)/256, 256, 0, stream>>>(dst, deg);
    k_wconv<<<(CC*HH+255)/256, 256, 0, stream>>>(W0, W1, Wh1, Wt0, Wt1, Wth1);

    int nscan = (NN+255)/256;
    k_scan1<<<nscan, 256, 0, stream>>>(deg, partial, dinv);
    k_scan2<<<1,     256, 0, stream>>>(partial, batch, cnt);
    k_scan3<<<nscan, 256, 0, stream>>>(deg, partial, csr_off);
    k_fill <<<(EE+255)/256, 256, 0, stream>>>(src, dst, csr_off, fillcnt, csr_src);

    int gemm_grid = (MR+63)/64;
    int nred = (GG*FD + 255)/256;

    // layer 0: 768 -> 192 (raw fp32 A = x)
    k_gemm_mfma<1,0,false><<<gemm_grid, 256, 0, stream>>>(
        x, nullptr, Wt0, nullptr, hb0, nullptr, nullptr,
        nullptr, nullptr,
        nullptr, nullptr, nullptr, nullptr, nullptr,
        nullptr, nullptr, nullptr, nullptr, nullptr, MR, CC);
    k_agg<<<NN, 192, 0, stream>>>((const ushort*)hb0, csr_src, csr_off, deg, dinv, b0, batch,
                                  agg0, s0m8, s0q8);
    k_gn_reduce<<<nred, 256, 0, stream>>>(s0m8, s0q8, f0m, f0q);

    // layer 1: A = gelu(gn0(agg0)) fused into GEMM A-staging; 192 -> 192
    k_gemm_mfma<1,1,false><<<gemm_grid, 256, 0, stream>>>(
        agg0, nullptr, Wt1, nullptr, hb1, nullptr, nullptr,
        batch, cnt,
        f0m, f0q, gn0_w, gn0_b, gn0_a,
        nullptr, nullptr, nullptr, nullptr, nullptr, MR, HH);
    k_agg<<<NN, 192, 0, stream>>>((const ushort*)hb1, csr_src, csr_off, deg, dinv, b1, batch,
                                  agg1, s1m8, s1q8);
    k_gn_reduce<<<nred, 256, 0, stream>>>(s1m8, s1q8, f1m, f1q);

    // fused head: A = gelu(gn1(agg1)) + gelu(gn0(agg0)); out = gelu(A@Wh1+bh1)@Wh2+bh2
    k_gemm_mfma<2,2,true><<<gemm_grid, 256, 0, stream>>>(
        agg1, agg0, Wth1, bh1, out, Wh2, bh2,
        batch, cnt,
        f1m, f1q, gn1_w, gn1_b, gn1_a,
        f0m, f0q, gn0_w, gn0_b, gn0_a, MR, HH);
}

// Round 5
// 973.304 us; speedup vs baseline: 2.2317x; 2.2317x over previous
//
#include <hip/hip_runtime.h>
#include <math.h>

#define NN   50000
#define TT   2
#define CC   768
#define GG   16
#define EE   800000
#define HH   192
#define OUTD 3
#define MR   (NN*TT)   // 100000 rows
#define FD   (TT*HH)   // 384 features per node
#define EPS_GN 1e-5f
#define GN_CHUNK 32

typedef __attribute__((ext_vector_type(8))) short bf16x8;
typedef __attribute__((ext_vector_type(4))) float f32x4;

__device__ __forceinline__ float gelu_exact(float x){
    return 0.5f * x * (1.0f + erff(x * 0.70710678118654752440f));
}

__device__ __forceinline__ short f2b(float f){   // RNE float->bf16
    unsigned u = __float_as_uint(f);
    unsigned r = (u + 0x7FFFu + ((u>>16)&1u)) >> 16;
    return (short)r;
}
__device__ __forceinline__ float b2f(unsigned short u){
    return __uint_as_float(((unsigned)u)<<16);
}

// ---------- degree ----------
__global__ __launch_bounds__(256) void k_deg(const int* __restrict__ dst, float* __restrict__ deg){
    int e = blockIdx.x*256 + threadIdx.x;
    if(e < EE) atomicAdd(&deg[dst[e]], 1.0f);
}

// ---------- weight convert: W[K][192] fp32 -> Wt[192][K] bf16 ----------
__global__ __launch_bounds__(256) void k_wconv(const float* __restrict__ W0, const float* __restrict__ W1,
                                               const float* __restrict__ Wh1,
                                               short* __restrict__ Wt0, short* __restrict__ Wt1,
                                               short* __restrict__ Wth1){
    int i = blockIdx.x*256 + threadIdx.x;
    if(i < CC*HH){
        int k = i / HH, n = i % HH;
        Wt0[(size_t)n*CC + k] = f2b(W0[i]);
    }
    if(i < HH*HH){
        int k = i / HH, n = i % HH;
        Wt1 [(size_t)n*HH + k] = f2b(W1[i]);
        Wth1[(size_t)n*HH + k] = f2b(Wh1[i]);
    }
}

// ---------- CSR build (scan1 also emits dinv; scan2 also emits cnt) ----------
__global__ __launch_bounds__(256) void k_scan1(const float* __restrict__ deg, int* __restrict__ partial,
                                               float* __restrict__ dinv){
    __shared__ int s[256];
    int t = threadIdx.x;
    int i = blockIdx.x*256 + t;
    float dv = (i < NN) ? deg[i] : 0.f;
    if(i < NN) dinv[i] = rsqrtf(dv + 1.0f);
    int v = (int)dv;
    s[t] = v; __syncthreads();
    for(int off=128; off>0; off>>=1){ if(t < off) s[t] += s[t+off]; __syncthreads(); }
    if(t == 0) partial[blockIdx.x] = s[0];
}

__global__ __launch_bounds__(256) void k_scan2(int* __restrict__ partial, const int* __restrict__ batch,
                                               float* __restrict__ cnt){
    __shared__ int s[256];
    int t = threadIdx.x;
    if(t < GG){   // fused group-count (batch is sorted)
        int g = t;
        int lo0=0, hi=NN;
        while(lo0<hi){ int mid=(lo0+hi)>>1; if(batch[mid] < g) lo0=mid+1; else hi=mid; }
        int lo1=lo0; hi=NN;
        while(lo1<hi){ int mid=(lo1+hi)>>1; if(batch[mid] < g+1) lo1=mid+1; else hi=mid; }
        cnt[g] = (float)(lo1 - lo0);
    }
    int v = partial[t];
    s[t] = v; __syncthreads();
    for(int off=1; off<256; off<<=1){
        int x = (t >= off) ? s[t-off] : 0;
        __syncthreads();
        s[t] += x;
        __syncthreads();
    }
    partial[t] = s[t] - v;
}

__global__ __launch_bounds__(256) void k_scan3(const float* __restrict__ deg, const int* __restrict__ partial,
                                               int* __restrict__ csr_off){
    __shared__ int s[256];
    int t = threadIdx.x;
    int i = blockIdx.x*256 + t;
    int v = (i < NN) ? (int)deg[i] : 0;
    s[t] = v; __syncthreads();
    for(int off=1; off<256; off<<=1){
        int x = (t >= off) ? s[t-off] : 0;
        __syncthreads();
        s[t] += x;
        __syncthreads();
    }
    if(i < NN) csr_off[i] = partial[blockIdx.x] + s[t] - v;
}

__global__ __launch_bounds__(256) void k_fill(const int* __restrict__ src, const int* __restrict__ dst,
                                              const int* __restrict__ csr_off, int* __restrict__ fillcnt,
                                              int* __restrict__ csr_src){
    int e = blockIdx.x*256 + threadIdx.x;
    if(e < EE){
        int d = dst[e];
        int pos = csr_off[d] + atomicAdd(&fillcnt[d], 1);
        csr_src[pos] = src[e];
    }
}

// ---------- GraphNorm+GELU on 8 register-resident values ----------
__device__ __forceinline__ void gn8r(float4 u0, float4 u1,
                                     const float* __restrict__ sm, const float* __restrict__ sq,
                                     int sb, int hb_,
                                     const float* __restrict__ wg, const float* __restrict__ bg,
                                     const float* __restrict__ ag, float ic, float v[8]){
    float4 m0 = *(const float4*)(sm+sb),   m1 = *(const float4*)(sm+sb+4);
    float4 q0 = *(const float4*)(sq+sb),   q1 = *(const float4*)(sq+sb+4);
    float4 w0 = *(const float4*)(wg+hb_),  w1 = *(const float4*)(wg+hb_+4);
    float4 b0 = *(const float4*)(bg+hb_),  b1 = *(const float4*)(bg+hb_+4);
    float4 a0 = *(const float4*)(ag+hb_),  a1 = *(const float4*)(ag+hb_+4);
    float uu[8]={u0.x,u0.y,u0.z,u0.w,u1.x,u1.y,u1.z,u1.w};
    float mm[8]={m0.x,m0.y,m0.z,m0.w,m1.x,m1.y,m1.z,m1.w};
    float qq[8]={q0.x,q0.y,q0.z,q0.w,q1.x,q1.y,q1.z,q1.w};
    float ww[8]={w0.x,w0.y,w0.z,w0.w,w1.x,w1.y,w1.z,w1.w};
    float bb[8]={b0.x,b0.y,b0.z,b0.w,b1.x,b1.y,b1.z,b1.w};
    float aa[8]={a0.x,a0.y,a0.z,a0.w,a1.x,a1.y,a1.z,a1.w};
    #pragma unroll
    for(int j=0;j<8;j++){
        float mean = mm[j]*ic, ex2 = qq[j]*ic, al = aa[j];
        float var = ex2 - (2.0f*al - al*al)*mean*mean;
        float t = ww[j]*(uu[j] - al*mean)*rsqrtf(var + EPS_GN) + bb[j];
        v[j] = gelu_exact(t);
    }
}

// ---------- bf16 MFMA GEMM (2-phase register prefetch; LDS-staged A and B) ----------
// MODE 1: write bf16 C.  MODE 2: head-fused -> out[M][3] = gelu(C+bias) @ W2 + b2
// NORM 0: A raw fp32.  NORM 1: A = gelu(gn(A1; stats1)).  NORM 2: A = gelu(gn(A1;s1)) + gelu(gn(A0;s0))
template<int MODE, int NORM, bool BIAS>
__global__ __launch_bounds__(256) void k_gemm_mfma(
        const float* __restrict__ A1, const float* __restrict__ A0,
        const short* __restrict__ Bt,
        const float* __restrict__ bias, void* __restrict__ Cv,
        const float* __restrict__ W2, const float* __restrict__ b2,
        const int* __restrict__ batch, const float* __restrict__ cnt,
        const float* __restrict__ sm1, const float* __restrict__ sq1,
        const float* __restrict__ wg1, const float* __restrict__ bg1, const float* __restrict__ ag1,
        const float* __restrict__ sm0, const float* __restrict__ sq0,
        const float* __restrict__ wg0, const float* __restrict__ bg0, const float* __restrict__ ag0,
        int Mrows, int Kdim){
    __shared__ short As[64][40];
    __shared__ short Bs[192][40];
    int tid = threadIdx.x;
    int bm = blockIdx.x*64;
    int wv = tid>>6, lane = tid&63;
    int lm = lane&15, lq = lane>>4;

    f32x4 acc[12];
    #pragma unroll
    for(int i=0;i<12;i++) acc[i] = (f32x4){0.f,0.f,0.f,0.f};

    int ar = tid>>2, akg = (tid&3)<<3;
    int row = bm + ar;
    bool aok = row < Mrows;
    const float* Ap1 = A1 + (size_t)row*Kdim + akg;
    const float* Ap0 = (NORM==2) ? (A0 + (size_t)row*Kdim + akg) : nullptr;
    int g = 0, tT = 0; float ic = 0.f;
    if(NORM >= 1 && aok){
        int nn = row>>1; tT = row&1;
        g = batch[nn];
        ic = 1.0f / cnt[g];
    }

    // register staging state (prefetched one K-step ahead)
    float4 ra0 = make_float4(0,0,0,0), ra1 = ra0, rb0 = ra0, rb1 = ra0;
    bf16x8 bv[3];
    if(aok){
        ra0 = *(const float4*)(Ap1); ra1 = *(const float4*)(Ap1 + 4);
        if(NORM==2){ rb0 = *(const float4*)(Ap0); rb1 = *(const float4*)(Ap0 + 4); }
    }
    #pragma unroll
    for(int i=0;i<3;i++){
        int idx = tid + i*256;
        int n = idx>>2, kg = (idx&3)<<3;
        bv[i] = *(const bf16x8*)(Bt + (size_t)n*Kdim + kg);
    }

    for(int k0 = 0; k0 < Kdim; k0 += 32){
        // convert the prefetched A regs -> bf16 fragment (VALU only)
        bf16x8 ap = {};
        if(aok){
            if(NORM == 0){
                ap[0]=f2b(ra0.x); ap[1]=f2b(ra0.y); ap[2]=f2b(ra0.z); ap[3]=f2b(ra0.w);
                ap[4]=f2b(ra1.x); ap[5]=f2b(ra1.y); ap[6]=f2b(ra1.z); ap[7]=f2b(ra1.w);
            } else {
                int hb_ = akg + k0;            // per-channel index (Kdim==HH here)
                int sb  = g*FD + tT*HH + hb_;
                float v[8];
                gn8r(ra0, ra1, sm1, sq1, sb, hb_, wg1, bg1, ag1, ic, v);
                if(NORM == 2){
                    float v0[8];
                    gn8r(rb0, rb1, sm0, sq0, sb, hb_, wg0, bg0, ag0, ic, v0);
                    #pragma unroll
                    for(int j=0;j<8;j++) v[j] += v0[j];
                }
                #pragma unroll
                for(int j=0;j<8;j++) ap[j] = f2b(v[j]);
            }
        }
        bf16x8 bw0 = bv[0], bw1 = bv[1], bw2 = bv[2];
        __syncthreads();
        *(bf16x8*)&As[ar][akg] = ap;
        {
            int idx0 = tid, idx1 = tid+256, idx2 = tid+512;
            *(bf16x8*)&Bs[idx0>>2][(idx0&3)<<3] = bw0;
            *(bf16x8*)&Bs[idx1>>2][(idx1&3)<<3] = bw1;
            *(bf16x8*)&Bs[idx2>>2][(idx2&3)<<3] = bw2;
        }
        __syncthreads();
        // issue next K-step's global loads before the MFMA cluster
        int k1 = k0 + 32;
        if(k1 < Kdim){
            if(aok){
                ra0 = *(const float4*)(Ap1 + k1); ra1 = *(const float4*)(Ap1 + k1 + 4);
                if(NORM==2){ rb0 = *(const float4*)(Ap0 + k1); rb1 = *(const float4*)(Ap0 + k1 + 4); }
            }
            #pragma unroll
            for(int i=0;i<3;i++){
                int idx = tid + i*256;
                int n = idx>>2, kg = (idx&3)<<3;
                bv[i] = *(const bf16x8*)(Bt + (size_t)n*Kdim + k1 + kg);
            }
        }
        bf16x8 af = *(const bf16x8*)&As[wv*16 + lm][lq*8];
        #pragma unroll
        for(int ct=0; ct<12; ct++){
            bf16x8 bfr = *(const bf16x8*)&Bs[ct*16 + lm][lq*8];
            acc[ct] = __builtin_amdgcn_mfma_f32_16x16x32_bf16(af, bfr, acc[ct], 0, 0, 0);
        }
    }

    if(MODE == 1){
        short* C = (short*)Cv;
        #pragma unroll
        for(int ct=0; ct<12; ct++){
            int col = ct*16 + lm;
            float bs = BIAS ? bias[col] : 0.f;
            #pragma unroll
            for(int r=0; r<4; r++){
                int orow = bm + wv*16 + lq*4 + r;
                if(orow < Mrows) C[(size_t)orow*HH + col] = f2b(acc[ct][r] + bs);
            }
        }
    } else {  // MODE 2: fused head
        float hs[4][3] = {};
        #pragma unroll
        for(int ct=0; ct<12; ct++){
            int col = ct*16 + lm;
            float bs = bias[col];
            float w20 = W2[col*3+0], w21 = W2[col*3+1], w22 = W2[col*3+2];
            #pragma unroll
            for(int r=0; r<4; r++){
                float gl = gelu_exact(acc[ct][r] + bs);
                hs[r][0] += gl*w20; hs[r][1] += gl*w21; hs[r][2] += gl*w22;
            }
        }
        #pragma unroll
        for(int off=1; off<16; off<<=1){
            #pragma unroll
            for(int r=0;r<4;r++){
                hs[r][0] += __shfl_xor(hs[r][0], off);
                hs[r][1] += __shfl_xor(hs[r][1], off);
                hs[r][2] += __shfl_xor(hs[r][2], off);
            }
        }
        if(lm == 0){
            float* O = (float*)Cv;
            #pragma unroll
            for(int r=0;r<4;r++){
                int orow = bm + wv*16 + lq*4 + r;
                if(orow < Mrows){
                    O[(size_t)orow*3+0] = hs[r][0] + b2[0];
                    O[(size_t)orow*3+1] = hs[r][1] + b2[1];
                    O[(size_t)orow*3+2] = hs[r][2] + b2[2];
                }
            }
        }
    }
}

// ---------- GCN aggregation: wave-per-node, no LDS, shfl-broadcast indices ----------
__global__ __launch_bounds__(256) void k_agg(const ushort* __restrict__ hw, const int* __restrict__ csr_src,
                                             const int* __restrict__ csr_off, const float* __restrict__ deg,
                                             const float* __restrict__ dinv, const float* __restrict__ bias,
                                             float* __restrict__ out){
    int lane = threadIdx.x & 63;
    int n = blockIdx.x*4 + (threadIdx.x>>6);
    if(n >= NN) return;
    float di = dinv[n];
    const ushort2* H2 = (const ushort2*)hw;
    size_t rb = (size_t)n*192 + lane*3;       // lane covers ushort2 slots lane*3 .. +2
    ushort2 s0v = H2[rb], s1v = H2[rb+1], s2v = H2[rb+2];
    float self = di*di;
    float a0 = b2f(s0v.x)*self, a1 = b2f(s0v.y)*self;
    float a2 = b2f(s1v.x)*self, a3 = b2f(s1v.y)*self;
    float a4 = b2f(s2v.x)*self, a5 = b2f(s2v.y)*self;
    int beg = csr_off[n];
    int end = beg + (int)deg[n];
    for(int base = beg; base < end; base += 64){
        int m = min(64, end - base);
        int e = 0; float we = 0.f;
        if(lane < m){ e = csr_src[base + lane]; we = dinv[e]*di; }
        int j = 0;
        for(; j+4 <= m; j += 4){
            int   sA=__shfl(e,j),  sB=__shfl(e,j+1),  sC=__shfl(e,j+2),  sD=__shfl(e,j+3);
            float wA=__shfl(we,j), wB=__shfl(we,j+1), wC=__shfl(we,j+2), wD=__shfl(we,j+3);
            size_t bA=(size_t)sA*192+lane*3, bB=(size_t)sB*192+lane*3;
            size_t bC=(size_t)sC*192+lane*3, bD=(size_t)sD*192+lane*3;
            ushort2 vA0=H2[bA], vA1=H2[bA+1], vA2=H2[bA+2];
            ushort2 vB0=H2[bB], vB1=H2[bB+1], vB2=H2[bB+2];
            ushort2 vC0=H2[bC], vC1=H2[bC+1], vC2=H2[bC+2];
            ushort2 vD0=H2[bD], vD1=H2[bD+1], vD2=H2[bD+2];
            a0 += wA*b2f(vA0.x)+wB*b2f(vB0.x)+wC*b2f(vC0.x)+wD*b2f(vD0.x);
            a1 += wA*b2f(vA0.y)+wB*b2f(vB0.y)+wC*b2f(vC0.y)+wD*b2f(vD0.y);
            a2 += wA*b2f(vA1.x)+wB*b2f(vB1.x)+wC*b2f(vC1.x)+wD*b2f(vD1.x);
            a3 += wA*b2f(vA1.y)+wB*b2f(vB1.y)+wC*b2f(vC1.y)+wD*b2f(vD1.y);
            a4 += wA*b2f(vA2.x)+wB*b2f(vB2.x)+wC*b2f(vC2.x)+wD*b2f(vD2.x);
            a5 += wA*b2f(vA2.y)+wB*b2f(vB2.y)+wC*b2f(vC2.y)+wD*b2f(vD2.y);
        }
        for(; j < m; j++){
            int s = __shfl(e, j); float ww = __shfl(we, j);
            size_t sb = (size_t)s*192 + lane*3;
            ushort2 v0=H2[sb], v1=H2[sb+1], v2=H2[sb+2];
            a0 += ww*b2f(v0.x); a1 += ww*b2f(v0.y);
            a2 += ww*b2f(v1.x); a3 += ww*b2f(v1.y);
            a4 += ww*b2f(v2.x); a5 += ww*b2f(v2.y);
        }
    }
    int f0 = lane*6;
    float r[6] = {a0,a1,a2,a3,a4,a5};
    float* O = out + (size_t)n*FD + f0;
    #pragma unroll
    for(int i=0;i<6;i++){
        int f = f0 + i;
        int hh = (f < HH) ? f : f - HH;
        O[i] = r[i] + bias[hh];
    }
}

// ---------- GraphNorm stats: quad-preload, sorted-batch fast path ----------
__global__ __launch_bounds__(384) void k_gn_stats(const float* __restrict__ h, const int* __restrict__ batch,
                                                  float* __restrict__ ssum, float* __restrict__ ssq){
    int f = threadIdx.x;
    int n0 = blockIdx.x*GN_CHUNK;
    int n1 = min(n0 + GN_CHUNK, NN);
    int g = batch[n0];
    float a = 0.f, a2 = 0.f;
    int n = n0;
    for(; n+4 <= n1; n += 4){
        float v0 = h[(size_t)n*FD + f];
        float v1 = h[(size_t)(n+1)*FD + f];
        float v2 = h[(size_t)(n+2)*FD + f];
        float v3 = h[(size_t)(n+3)*FD + f];
        int b3 = batch[n+3];
        if(b3 == g){   // sorted => all four rows in run g
            a  += v0+v1+v2+v3;
            a2 += v0*v0+v1*v1+v2*v2+v3*v3;
        } else {
            float vv[4] = {v0,v1,v2,v3};
            #pragma unroll
            for(int q=0;q<4;q++){
                int gn = batch[n+q];
                if(gn != g){
                    atomicAdd(&ssum[g*FD + f], a);
                    atomicAdd(&ssq [g*FD + f], a2);
                    a = 0.f; a2 = 0.f; g = gn;
                }
                a += vv[q]; a2 += vv[q]*vv[q];
            }
        }
    }
    for(; n < n1; n++){
        int gn = batch[n];
        if(gn != g){
            atomicAdd(&ssum[g*FD + f], a);
            atomicAdd(&ssq [g*FD + f], a2);
            a = 0.f; a2 = 0.f; g = gn;
        }
        float v = h[(size_t)n*FD + f];
        a += v; a2 += v*v;
    }
    atomicAdd(&ssum[g*FD + f], a);
    atomicAdd(&ssq [g*FD + f], a2);
}

extern "C" void kernel_launch(void* const* d_in, const int* in_sizes, int n_in,
                              void* d_out, int out_size, void* d_ws, size_t ws_size,
                              hipStream_t stream){
    const float* x     = (const float*)d_in[0];
    const int*   batch = (const int*)d_in[1];
    const int*   ei    = (const int*)d_in[2];
    const int*   src   = ei;
    const int*   dst   = ei + EE;
    const float* W0    = (const float*)d_in[3];
    const float* b0    = (const float*)d_in[4];
    const float* gn0_w = (const float*)d_in[5];
    const float* gn0_b = (const float*)d_in[6];
    const float* gn0_a = (const float*)d_in[7];
    const float* W1    = (const float*)d_in[8];
    const float* b1    = (const float*)d_in[9];
    const float* gn1_w = (const float*)d_in[10];
    const float* gn1_b = (const float*)d_in[11];
    const float* gn1_a = (const float*)d_in[12];
    const float* Wh1   = (const float*)d_in[13];
    const float* bh1   = (const float*)d_in[14];
    const float* Wh2   = (const float*)d_in[15];
    const float* bh2   = (const float*)d_in[16];
    float* out = (float*)d_out;

    char* w = (char*)d_ws;
    auto alloc = [&](size_t bytes)->void*{
        void* p = (void*)w;
        w += (bytes + 255) & ~(size_t)255;
        return p;
    };
    char* zbase = w;
    float* deg     = (float*)alloc((size_t)NN*4);
    int*   fillcnt = (int*)  alloc((size_t)NN*4);
    int*   partial = (int*)  alloc(256*4);
    float* s0m     = (float*)alloc((size_t)GG*FD*4);
    float* s0q     = (float*)alloc((size_t)GG*FD*4);
    float* s1m     = (float*)alloc((size_t)GG*FD*4);
    float* s1q     = (float*)alloc((size_t)GG*FD*4);
    size_t zbytes = (size_t)(w - zbase);
    float* cnt     = (float*)alloc((size_t)GG*4);
    float* dinv    = (float*)alloc((size_t)NN*4);
    int*   csr_off = (int*)  alloc((size_t)NN*4);
    int*   csr_src = (int*)  alloc((size_t)EE*4);
    short* Wt0     = (short*)alloc((size_t)HH*CC*2);
    short* Wt1     = (short*)alloc((size_t)HH*HH*2);
    short* Wth1    = (short*)alloc((size_t)HH*HH*2);
    short* hb0     = (short*)alloc((size_t)MR*HH*2);   // bf16 GEMM0 output (agg0 input)
    short* hb1     = (short*)alloc((size_t)MR*HH*2);   // bf16 GEMM1 output (agg1 input)
    float* agg0    = (float*)alloc((size_t)MR*HH*4);   // fp32 pre-norm layer0 (kept for residual)
    float* agg1    = (float*)alloc((size_t)MR*HH*4);   // fp32 pre-norm layer1

    hipMemsetAsync(zbase, 0, zbytes, stream);

    k_deg  <<<(EE+255)/256, 256, 0, stream>>>(dst, deg);
    k_wconv<<<(CC*HH+255)/256, 256, 0, stream>>>(W0, W1, Wh1, Wt0, Wt1, Wth1);

    int nscan = (NN+255)/256;
    k_scan1<<<nscan, 256, 0, stream>>>(deg, partial, dinv);
    k_scan2<<<1,     256, 0, stream>>>(partial, batch, cnt);
    k_scan3<<<nscan, 256, 0, stream>>>(deg, partial, csr_off);
    k_fill <<<(EE+255)/256, 256, 0, stream>>>(src, dst, csr_off, fillcnt, csr_src);

    int gemm_grid = (MR+63)/64;
    int agg_grid  = (NN+3)/4;
    int ngn = (NN + GN_CHUNK - 1)/GN_CHUNK;

    // layer 0: 768 -> 192 (raw fp32 A = x)
    k_gemm_mfma<1,0,false><<<gemm_grid, 256, 0, stream>>>(
        x, nullptr, Wt0, nullptr, hb0, nullptr, nullptr,
        nullptr, nullptr,
        nullptr, nullptr, nullptr, nullptr, nullptr,
        nullptr, nullptr, nullptr, nullptr, nullptr, MR, CC);
    k_agg<<<agg_grid, 256, 0, stream>>>((const ushort*)hb0, csr_src, csr_off, deg, dinv, b0, agg0);
    k_gn_stats<<<ngn, 384, 0, stream>>>(agg0, batch, s0m, s0q);

    // layer 1: A = gelu(gn0(agg0)) fused into GEMM A-staging; 192 -> 192
    k_gemm_mfma<1,1,false><<<gemm_grid, 256, 0, stream>>>(
        agg0, nullptr, Wt1, nullptr, hb1, nullptr, nullptr,
        batch, cnt,
        s0m, s0q, gn0_w, gn0_b, gn0_a,
        nullptr, nullptr, nullptr, nullptr, nullptr, MR, HH);
    k_agg<<<agg_grid, 256, 0, stream>>>((const ushort*)hb1, csr_src, csr_off, deg, dinv, b1, agg1);
    k_gn_stats<<<ngn, 384, 0, stream>>>(agg1, batch, s1m, s1q);

    // fused head: A = gelu(gn1(agg1)) + gelu(gn0(agg0)); out = gelu(A@Wh1+bh1)@Wh2+bh2
    k_gemm_mfma<2,2,true><<<gemm_grid, 256, 0, stream>>>(
        agg1, agg0, Wth1, bh1, out, Wh2, bh2,
        batch, cnt,
        s1m, s1q, gn1_w, gn1_b, gn1_a,
        s0m, s0q, gn0_w, gn0_b, gn0_a, MR, HH);
}